// Round 1
// baseline (260.438 us; speedup 1.0000x reference)
//
#include <hip/hip_runtime.h>
#include <hip/hip_bf16.h>

#define K_DIM 64

typedef __attribute__((ext_vector_type(8))) __bf16 bf16x8;
typedef __attribute__((ext_vector_type(4))) float  f32x4;

// Kernel 1: row-normalize A and B (fp32) -> bf16 rows in workspace.
// One wave per row: 64 lanes == 64 elements.
__global__ __launch_bounds__(256) void normalize_bf16_kernel(
    const float* __restrict__ A, const float* __restrict__ B,
    __hip_bfloat16* __restrict__ An, __hip_bfloat16* __restrict__ Bn,
    int nA, int nB)
{
    int row  = blockIdx.x * 4 + (threadIdx.x >> 6);
    int lane = threadIdx.x & 63;
    if (row >= nA + nB) return;
    const float*      src = (row < nA) ? A  : B;
    __hip_bfloat16*   dst = (row < nA) ? An : Bn;
    int r = (row < nA) ? row : row - nA;

    float v = src[(size_t)r * K_DIM + lane];
    float s = v * v;
    #pragma unroll
    for (int off = 32; off >= 1; off >>= 1)
        s += __shfl_xor(s, off, 64);
    float inv = 1.0f / fmaxf(sqrtf(s), 1e-8f);   // matches max(||a||, eps)
    dst[(size_t)r * K_DIM + lane] = __float2bfloat16(v * inv);
}

// Kernel 2: C = An * Bn^T via bf16 MFMA.
// 128x128 block tile, 4 waves; each wave does a 64x64 region as 4x4 tiles of
// 16x16, K=64 in 2 k-steps of mfma_f32_16x16x32_bf16.
// Fragments come straight from global (inputs are 2 MB each -> L1/L2 resident).
__global__ __launch_bounds__(256) void cosine_gemm_kernel(
    const f32x4* __restrict__ An, const f32x4* __restrict__ Bn,
    float* __restrict__ C, int N)
{
    const int lane = threadIdx.x & 63;
    const int wave = threadIdx.x >> 6;
    const int wm   = wave >> 1;       // 0..1
    const int wn   = wave & 1;        // 0..1
    const int l16  = lane & 15;
    const int quad = lane >> 4;       // 0..3
    const int bm   = blockIdx.x * 128;
    const int bn   = blockIdx.y * 128;

    // A fragment: A[m = tile_row + l16][k = ks*32 + quad*8 + j], j=0..7 (16 B)
    // row is 64 bf16 = 8 float4s; float4 index within row = ks*4 + quad
    bf16x8 afrag[4][2], bfrag[4][2];
    #pragma unroll
    for (int t = 0; t < 4; ++t) {
        size_t ra = (size_t)(bm + wm * 64 + t * 16 + l16) * 8;
        size_t rb = (size_t)(bn + wn * 64 + t * 16 + l16) * 8;
        #pragma unroll
        for (int ks = 0; ks < 2; ++ks) {
            afrag[t][ks] = __builtin_bit_cast(bf16x8, An[ra + ks * 4 + quad]);
            bfrag[t][ks] = __builtin_bit_cast(bf16x8, Bn[rb + ks * 4 + quad]);
        }
    }

    #pragma unroll
    for (int tm = 0; tm < 4; ++tm) {
        #pragma unroll
        for (int tn = 0; tn < 4; ++tn) {
            f32x4 acc = {0.f, 0.f, 0.f, 0.f};
            acc = __builtin_amdgcn_mfma_f32_16x16x32_bf16(afrag[tm][0], bfrag[tn][0], acc, 0, 0, 0);
            acc = __builtin_amdgcn_mfma_f32_16x16x32_bf16(afrag[tm][1], bfrag[tn][1], acc, 0, 0, 0);
            // C/D layout (measured, m89/m91): col = lane&15, row = quad*4 + reg
            int col  = bn + wn * 64 + tn * 16 + l16;
            int row0 = bm + wm * 64 + tm * 16 + quad * 4;
            #pragma unroll
            for (int r = 0; r < 4; ++r)
                C[(size_t)(row0 + r) * N + col] = acc[r];
        }
    }
}

extern "C" void kernel_launch(void* const* d_in, const int* in_sizes, int n_in,
                              void* d_out, int out_size, void* d_ws, size_t ws_size,
                              hipStream_t stream) {
    const float* A = (const float*)d_in[0];
    const float* B = (const float*)d_in[1];
    int nA = in_sizes[0] / K_DIM;   // 8192
    int nB = in_sizes[1] / K_DIM;   // 8192
    float* C = (float*)d_out;

    __hip_bfloat16* An = (__hip_bfloat16*)d_ws;
    __hip_bfloat16* Bn = An + (size_t)nA * K_DIM;   // 2 MB total in d_ws

    int totalRows = nA + nB;
    normalize_bf16_kernel<<<dim3((totalRows + 3) / 4), dim3(256), 0, stream>>>(
        A, B, An, Bn, nA, nB);

    dim3 grid(nA / 128, nB / 128);
    cosine_gemm_kernel<<<grid, dim3(256), 0, stream>>>(
        (const f32x4*)An, (const f32x4*)Bn, C, nB);
}

// Round 2
// 257.691 us; speedup vs baseline: 1.0107x; 1.0107x over previous
//
#include <hip/hip_runtime.h>
#include <hip/hip_bf16.h>

#define K_DIM 64

typedef __attribute__((ext_vector_type(8))) __bf16 bf16x8;
typedef __attribute__((ext_vector_type(4))) float  f32x4;

// Kernel 1: row-normalize A and B (fp32) -> bf16 rows in workspace.
// One wave per row: 64 lanes == 64 elements.
__global__ __launch_bounds__(256) void normalize_bf16_kernel(
    const float* __restrict__ A, const float* __restrict__ B,
    __hip_bfloat16* __restrict__ An, __hip_bfloat16* __restrict__ Bn,
    int nA, int nB)
{
    int row  = blockIdx.x * 4 + (threadIdx.x >> 6);
    int lane = threadIdx.x & 63;
    if (row >= nA + nB) return;
    const float*      src = (row < nA) ? A  : B;
    __hip_bfloat16*   dst = (row < nA) ? An : Bn;
    int r = (row < nA) ? row : row - nA;

    float v = src[(size_t)r * K_DIM + lane];
    float s = v * v;
    #pragma unroll
    for (int off = 32; off >= 1; off >>= 1)
        s += __shfl_xor(s, off, 64);
    float inv = 1.0f / fmaxf(sqrtf(s), 1e-8f);   // matches max(||a||, eps)
    dst[(size_t)r * K_DIM + lane] = __float2bfloat16(v * inv);
}

// Kernel 2: C = An * Bn^T via bf16 MFMA, write-roofline-targeted epilogue.
// 128x128 block tile, 4 waves; each wave owns a 64x64 region done as 4 slabs
// (tm) of 16 rows x 64 cols. Per slab: 8 MFMA -> per-wave LDS transpose ->
// float4 row-contiguous global stores (16 B/lane, 256 B runs per row).
// All LDS access patterns are <=2-way bank aliased (free on CDNA4, m136).
__global__ __launch_bounds__(256) void cosine_gemm_kernel(
    const f32x4* __restrict__ An, const f32x4* __restrict__ Bn,
    float* __restrict__ C, int N)
{
    // per-wave private staging buffer: 16 rows x (64+4) floats = 4352 B
    // pad +4: ds_write banks become 16*quad + 4r + l16 -> 2-way max.
    __shared__ float smem[4][16][68];

    const int lane = threadIdx.x & 63;
    const int wave = threadIdx.x >> 6;
    const int wm   = wave >> 1;       // 0..1
    const int wn   = wave & 1;        // 0..1
    const int l16  = lane & 15;
    const int quad = lane >> 4;       // 0..3
    const int gm0  = blockIdx.x * 128 + wm * 64;
    const int gn0  = blockIdx.y * 128 + wn * 64;

    float (*buf)[68] = smem[wave];

    // B fragments for all 4 tn tiles: B[n = gn0+t*16+l16][k = ks*32+quad*8+j]
    // row is 64 bf16 = 8 float4s; float4 index within row = ks*4 + quad
    bf16x8 bfrag[4][2];
    #pragma unroll
    for (int t = 0; t < 4; ++t) {
        size_t rb = (size_t)(gn0 + t * 16 + l16) * 8;
        bfrag[t][0] = __builtin_bit_cast(bf16x8, Bn[rb + quad]);
        bfrag[t][1] = __builtin_bit_cast(bf16x8, Bn[rb + 4 + quad]);
    }

    #pragma unroll
    for (int tm = 0; tm < 4; ++tm) {
        size_t ra = (size_t)(gm0 + tm * 16 + l16) * 8;
        bf16x8 a0 = __builtin_bit_cast(bf16x8, An[ra + quad]);
        bf16x8 a1 = __builtin_bit_cast(bf16x8, An[ra + 4 + quad]);

        f32x4 acc[4];
        #pragma unroll
        for (int tn = 0; tn < 4; ++tn) {
            f32x4 a = {0.f, 0.f, 0.f, 0.f};
            a = __builtin_amdgcn_mfma_f32_16x16x32_bf16(a0, bfrag[tn][0], a, 0, 0, 0);
            a = __builtin_amdgcn_mfma_f32_16x16x32_bf16(a1, bfrag[tn][1], a, 0, 0, 0);
            acc[tn] = a;
        }

        // Stage: C/D layout (m89/m91) is col = l16, row = quad*4 + r.
        // Per-wave buffer + same-wave DS ordering => no __syncthreads needed.
        #pragma unroll
        for (int tn = 0; tn < 4; ++tn)
            #pragma unroll
            for (int r = 0; r < 4; ++r)
                buf[quad * 4 + r][tn * 16 + l16] = acc[tn][r];

        // Drain: each lane emits one float4 per row-group; lanes 0-15 cover
        // one full 256 B row segment -> 4 contiguous segments per store inst.
        #pragma unroll
        for (int i = 0; i < 4; ++i) {
            int row = i * 4 + quad;
            f32x4 v = *(const f32x4*)&buf[row][l16 * 4];
            *(f32x4*)&C[(size_t)(gm0 + tm * 16 + row) * N + gn0 + l16 * 4] = v;
        }
    }
}

extern "C" void kernel_launch(void* const* d_in, const int* in_sizes, int n_in,
                              void* d_out, int out_size, void* d_ws, size_t ws_size,
                              hipStream_t stream) {
    const float* A = (const float*)d_in[0];
    const float* B = (const float*)d_in[1];
    int nA = in_sizes[0] / K_DIM;   // 8192
    int nB = in_sizes[1] / K_DIM;   // 8192
    float* C = (float*)d_out;

    __hip_bfloat16* An = (__hip_bfloat16*)d_ws;
    __hip_bfloat16* Bn = An + (size_t)nA * K_DIM;   // 2 MB total in d_ws

    int totalRows = nA + nB;
    normalize_bf16_kernel<<<dim3((totalRows + 3) / 4), dim3(256), 0, stream>>>(
        A, B, An, Bn, nA, nB);

    dim3 grid(nA / 128, nB / 128);
    cosine_gemm_kernel<<<grid, dim3(256), 0, stream>>>(
        (const f32x4*)An, (const f32x4*)Bn, C, nB);
}